// Round 1
// baseline (162.611 us; speedup 1.0000x reference)
//
#include <hip/hip_runtime.h>

// YOLOv1 head post-process: softmax+score, box decode, per-class greedy NMS.
// One block (256 thr = 4 waves) per batch image. Equivalence note: boxes with
// score < SCORE_T only ever suppress boxes even lower in sort order, which are
// zeroed by the final score filter anyway -> NMS restricted to candidates with
// score >= SCORE_T yields the identical output.

namespace {
constexpr int kS    = 7;
constexpr int kC    = 20;
constexpr int kFeat = 30;             // C + 5*BBOX
constexpr int kN    = kS * kS * 2;    // 98 boxes
constexpr int kRows = kN * kC;        // 1960
constexpr int kOutF = kRows * 6;      // 11760 floats per batch
constexpr float kIouT   = 0.5f;
constexpr float kScoreT = 0.05f;
}

__device__ __forceinline__ float iou_f(float ax1, float ay1, float ax2, float ay2,
                                       float bx1, float by1, float bx2, float by2) {
#pragma clang fp contract(off)
    float aa = fmaxf(ax2 - ax1, 0.f) * fmaxf(ay2 - ay1, 0.f);
    float ab = fmaxf(bx2 - bx1, 0.f) * fmaxf(by2 - by1, 0.f);
    float ix1 = fmaxf(ax1, bx1);
    float iy1 = fmaxf(ay1, by1);
    float ix2 = fminf(ax2, bx2);
    float iy2 = fminf(ay2, by2);
    float inter = fmaxf(ix2 - ix1, 0.f) * fmaxf(iy2 - iy1, 0.f);
    float uni = aa + ab - inter;
    return inter / fmaxf(uni, 1e-9f);
}

__global__ __launch_bounds__(256) void yolo_head_kernel(const float* __restrict__ x,
                                                        float* __restrict__ out) {
    __shared__ float xs[kS * kS * kFeat];          // 1470 raw input floats
    __shared__ float sc[kN * kC];                  // scores [n][c]
    __shared__ float bxs[kN * 4];                  // boxes  [n][x1,y1,x2,y2]
    __shared__ unsigned long long km[kC][2];       // keep bitmask per class

    const int b   = blockIdx.x;
    const int tid = threadIdx.x;
    const float* xb = x + (size_t)b * (kS * kS * kFeat);

    for (int e = tid; e < kS * kS * kFeat; e += 256) xs[e] = xb[e];
    __syncthreads();

    if (tid < kS * kS) {
#pragma clang fp contract(off)
        // softmax over 20 classes for this cell, then scores for both bboxes
        const int cell = tid;
        const float* p = &xs[cell * kFeat];
        float m = p[0];
        for (int c = 1; c < kC; ++c) m = fmaxf(m, p[c]);
        float e[kC];
        float sum = 0.f;
        for (int c = 0; c < kC; ++c) { e[c] = expf(p[c] - m); sum += e[c]; }
        float conf0 = p[28], conf1 = p[29];
        for (int c = 0; c < kC; ++c) {
            float pr = e[c] / sum;
            sc[(2 * cell) * kC + c]     = pr * conf0;
            sc[(2 * cell + 1) * kC + c] = pr * conf1;
        }
    } else if (tid >= 64 && tid < 64 + kN) {
#pragma clang fp contract(off)
        // box decode for box n
        const int n = tid - 64;
        const int cell = n >> 1, k = n & 1;
        const int gi = cell / kS, gj = cell % kS;   // gy=gi, gx=gj
        const float* p = &xs[cell * kFeat + kC + 4 * k];
        float cx = (p[0] + (float)gj) / 7.0f;
        float cy = (p[1] + (float)gi) / 7.0f;
        float w = p[2], h = p[3];
        float x1 = fminf(fmaxf(cx - w * 0.5f, 0.f), 1.f) * 448.f;
        float y1 = fminf(fmaxf(cy - h * 0.5f, 0.f), 1.f) * 448.f;
        float x2 = fminf(fmaxf(cx + w * 0.5f, 0.f), 1.f) * 448.f;
        float y2 = fminf(fmaxf(cy + h * 0.5f, 0.f), 1.f) * 448.f;
        bxs[n * 4 + 0] = x1;
        bxs[n * 4 + 1] = y1;
        bxs[n * 4 + 2] = x2;
        bxs[n * 4 + 3] = y2;
    }
    __syncthreads();

    // ---- per-class greedy NMS: wave wv handles classes wv, wv+4, ... ----
    const int wv = tid >> 6;
    const int lane = tid & 63;
    for (int c = wv; c < kC; c += 4) {
        const int n0 = lane;
        const int n1 = lane + 64;
        const bool v1 = (n1 < kN);
        float s0 = sc[n0 * kC + c];
        float s1 = v1 ? sc[n1 * kC + c] : -1e30f;
        bool c0 = (s0 >= kScoreT);
        bool c1 = v1 && (s1 >= kScoreT);
        float a0x1 = bxs[n0 * 4 + 0], a0y1 = bxs[n0 * 4 + 1];
        float a0x2 = bxs[n0 * 4 + 2], a0y2 = bxs[n0 * 4 + 3];
        float a1x1 = 0.f, a1y1 = 0.f, a1x2 = 0.f, a1y2 = 0.f;
        if (v1) {
            a1x1 = bxs[n1 * 4 + 0]; a1y1 = bxs[n1 * 4 + 1];
            a1x2 = bxs[n1 * 4 + 2]; a1y2 = bxs[n1 * 4 + 3];
        }
        bool k0 = false, k1 = false;

        for (;;) {
            // per-lane best remaining candidate (score desc, index asc)
            float bs;
            int bn;
            if (c0 && (!c1 || s0 >= s1)) { bs = s0; bn = n0; }
            else if (c1)                 { bs = s1; bn = n1; }
            else                         { bs = -1e30f; bn = 127; }
            // wave argmax, tie -> smaller index (matches stable argsort(-scores))
            for (int off = 32; off; off >>= 1) {
                float os = __shfl_xor(bs, off);
                int   on = __shfl_xor(bn, off);
                if (os > bs || (os == bs && on < bn)) { bs = os; bn = on; }
            }
            if (bn > kN - 1) break;   // no candidates left

            float kx1 = bxs[bn * 4 + 0], ky1 = bxs[bn * 4 + 1];
            float kx2 = bxs[bn * 4 + 2], ky2 = bxs[bn * 4 + 3];
            if (bn == n0) { k0 = true; c0 = false; }
            if (bn == n1) { k1 = true; c1 = false; }
            if (c0 && iou_f(kx1, ky1, kx2, ky2, a0x1, a0y1, a0x2, a0y2) > kIouT) c0 = false;
            if (c1 && iou_f(kx1, ky1, kx2, ky2, a1x1, a1y1, a1x2, a1y2) > kIouT) c1 = false;
        }
        unsigned long long m0 = __ballot(k0);
        unsigned long long m1 = __ballot(k1);
        if (lane == 0) { km[c][0] = m0; km[c][1] = m1; }
    }
    __syncthreads();

    // ---- output: rows r = n*C + c, fields [cls, x1,y1,x2,y2, score] * keep ----
    float* ob = out + (size_t)b * kOutF;
    for (int r = tid; r < kRows; r += 256) {
        const int n = r / kC;
        const int c = r - n * kC;
        const bool kp = (km[c][n >> 6] >> (n & 63)) & 1ull;
        const float m = kp ? 1.f : 0.f;
        float v0 = m * (float)c;
        float v1 = m * bxs[n * 4 + 0];
        float v2 = m * bxs[n * 4 + 1];
        float v3 = m * bxs[n * 4 + 2];
        float v4 = m * bxs[n * 4 + 3];
        float v5 = m * sc[n * kC + c];
        float2* o2 = reinterpret_cast<float2*>(ob + (size_t)r * 6);
        o2[0] = make_float2(v0, v1);
        o2[1] = make_float2(v2, v3);
        o2[2] = make_float2(v4, v5);
    }
}

extern "C" void kernel_launch(void* const* d_in, const int* in_sizes, int n_in,
                              void* d_out, int out_size, void* d_ws, size_t ws_size,
                              hipStream_t stream) {
    const float* x = (const float*)d_in[0];
    float* out = (float*)d_out;
    const int B = in_sizes[0] / (kS * kS * kFeat);   // 1024
    hipLaunchKernelGGL(yolo_head_kernel, dim3(B), dim3(256), 0, stream, x, out);
}

// Round 2
// 105.124 us; speedup vs baseline: 1.5469x; 1.5469x over previous
//
#include <hip/hip_runtime.h>

// YOLOv1 head post-process. One block (512 thr = 8 waves) per batch image.
// R2 redesign: the R1 kernel was latency-bound on the per-kept-box serial
// shuffle-argmax (K~20 candidates/class survive). Replace with:
//   (a) per-batch class-independent IoU>0.5 adjacency bitmasks (98x98),
//   (b) per-class candidate compaction + rank-count sort (stable, matches
//       jnp.argsort(-scores)),
//   (c) O(K) single-lane scan over ranks using the adj masks.
// Equivalence: boxes with score < SCORE_T only suppress boxes even later in
// sort order (all zeroed by the final score filter) -> NMS over candidates
// with score >= SCORE_T is exact. ORing the full symmetric adj row is safe:
// bits for earlier ranks are already decided when set.

namespace {
constexpr int kS    = 7;
constexpr int kC    = 20;
constexpr int kFeat = 30;             // C + 5*BBOX
constexpr int kN    = 98;             // S*S*2 boxes
constexpr int kRows = kN * kC;        // 1960
constexpr int kOutF = kRows * 6;      // 11760 floats per batch
constexpr int kT    = 512;            // threads per block (8 waves)
constexpr float kIouT   = 0.5f;
constexpr float kScoreT = 0.05f;
}

__device__ __forceinline__ float iou_f(float ax1, float ay1, float ax2, float ay2,
                                       float bx1, float by1, float bx2, float by2) {
#pragma clang fp contract(off)
    float aa = fmaxf(ax2 - ax1, 0.f) * fmaxf(ay2 - ay1, 0.f);
    float ab = fmaxf(bx2 - bx1, 0.f) * fmaxf(by2 - by1, 0.f);
    float ix1 = fmaxf(ax1, bx1);
    float iy1 = fmaxf(ay1, by1);
    float ix2 = fminf(ax2, bx2);
    float iy2 = fminf(ay2, by2);
    float inter = fmaxf(ix2 - ix1, 0.f) * fmaxf(iy2 - iy1, 0.f);
    float uni = aa + ab - inter;
    return inter / fmaxf(uni, 1e-9f);
}

__global__ __launch_bounds__(kT) void yolo_head_kernel(const float* __restrict__ x,
                                                       float* __restrict__ out) {
    __shared__ float xs[kS * kS * kFeat];          // 1470 raw input floats
    __shared__ float scT[kC * kN];                 // scores [c][n] (stride-1 in n)
    __shared__ float bxs[kN * 4];                  // boxes  [n][x1,y1,x2,y2]
    __shared__ unsigned adj[kN][4];                // IoU>T bitmask rows (128 bits)
    __shared__ float cscore[8][kN];                // per-wave compacted scores
    __shared__ unsigned short cidx[8][kN];         // per-wave compacted box idx
    __shared__ unsigned short ord[8][kN];          // per-wave rank -> box idx
    __shared__ unsigned km[kC][4];                 // keep bitmask per class

    const int b   = blockIdx.x;
    const int tid = threadIdx.x;
    const float* xb = x + (size_t)b * (kS * kS * kFeat);

    for (int e = tid; e < kS * kS * kFeat; e += kT) xs[e] = xb[e];
    __syncthreads();

    if (tid < kS * kS) {
#pragma clang fp contract(off)
        // softmax over 20 classes for this cell, then scores for both bboxes
        const int cell = tid;
        const float* p = &xs[cell * kFeat];
        float mx = p[0];
        for (int c = 1; c < kC; ++c) mx = fmaxf(mx, p[c]);
        float e[kC];
        float sum = 0.f;
        for (int c = 0; c < kC; ++c) { e[c] = expf(p[c] - mx); sum += e[c]; }
        float conf0 = p[28], conf1 = p[29];
        for (int c = 0; c < kC; ++c) {
            float pr = e[c] / sum;
            scT[c * kN + 2 * cell]     = pr * conf0;
            scT[c * kN + 2 * cell + 1] = pr * conf1;
        }
    } else if (tid >= 64 && tid < 64 + kN) {
#pragma clang fp contract(off)
        // box decode for box n
        const int n = tid - 64;
        const int cell = n >> 1, k = n & 1;
        const int gi = cell / kS, gj = cell % kS;   // gy=gi, gx=gj
        const float* p = &xs[cell * kFeat + kC + 4 * k];
        float cx = (p[0] + (float)gj) / 7.0f;
        float cy = (p[1] + (float)gi) / 7.0f;
        float w = p[2], h = p[3];
        bxs[n * 4 + 0] = fminf(fmaxf(cx - w * 0.5f, 0.f), 1.f) * 448.f;
        bxs[n * 4 + 1] = fminf(fmaxf(cy - h * 0.5f, 0.f), 1.f) * 448.f;
        bxs[n * 4 + 2] = fminf(fmaxf(cx + w * 0.5f, 0.f), 1.f) * 448.f;
        bxs[n * 4 + 3] = fminf(fmaxf(cy + h * 0.5f, 0.f), 1.f) * 448.f;
    }
    __syncthreads();

    // ---- per-batch IoU adjacency: thread (i = t%98, w = t/98) fills word w ----
    if (tid < 4 * kN) {
        const int i = tid % kN;       // consecutive lanes -> consecutive i
        const int w = tid / kN;       // wave-uniform word -> broadcast j-loads
        const float ax1 = bxs[i * 4 + 0], ay1 = bxs[i * 4 + 1];
        const float ax2 = bxs[i * 4 + 2], ay2 = bxs[i * 4 + 3];
        unsigned m = 0;
        const int j0 = 32 * w;
        const int j1 = (j0 + 32 < kN) ? (j0 + 32) : kN;
        for (int j = j0; j < j1; ++j) {
            float v = iou_f(ax1, ay1, ax2, ay2,
                            bxs[j * 4 + 0], bxs[j * 4 + 1],
                            bxs[j * 4 + 2], bxs[j * 4 + 3]);
            if (v > kIouT) m |= (1u << (j - j0));
        }
        adj[i][w] = m;
    }
    __syncthreads();

    // ---- per-class NMS: wave wv handles classes wv, wv+8, wv+16 ----
    const int wv = tid >> 6;
    const int lane = tid & 63;
    for (int c = wv; c < kC; c += 8) {
        // candidacy
        float s0 = scT[c * kN + lane];
        bool c0 = (s0 >= kScoreT);
        float s1 = 0.f;
        bool c1 = false;
        if (lane < kN - 64) {
            s1 = scT[c * kN + 64 + lane];
            c1 = (s1 >= kScoreT);
        }
        unsigned long long m0 = __ballot(c0);
        unsigned long long m1 = __ballot(c1);
        const int K0 = __popcll(m0);
        const int K  = K0 + __popcll(m1);
        // compact (index-ascending order preserved)
        if (c0) {
            int p = __popcll(m0 & ((1ull << lane) - 1ull));
            cidx[wv][p] = (unsigned short)lane;
            cscore[wv][p] = s0;
        }
        if (c1) {
            int p = K0 + __popcll(m1 & ((1ull << lane) - 1ull));
            cidx[wv][p] = (unsigned short)(lane + 64);
            cscore[wv][p] = s1;
        }
        __builtin_amdgcn_wave_barrier();
        // rank = # candidates strictly ahead in (score desc, index asc) order
        const bool o0 = (lane < K);
        const bool o1 = (lane + 64 < K);
        float t0 = o0 ? cscore[wv][lane] : 0.f;
        float t1 = o1 ? cscore[wv][lane + 64] : 0.f;
        int r0 = 0, r1 = 0;
        for (int q = 0; q < K; ++q) {
            float sq = cscore[wv][q];     // broadcast read
            r0 += ((sq > t0) || ((sq == t0) && (q < lane))) ? 1 : 0;
            r1 += ((sq > t1) || ((sq == t1) && (q < lane + 64))) ? 1 : 0;
        }
        if (o0) ord[wv][r0] = cidx[wv][lane];
        if (o1) ord[wv][r1] = cidx[wv][lane + 64];
        __builtin_amdgcn_wave_barrier();
        // greedy scan over ranks (single lane, O(K), no shuffles)
        if (lane == 0) {
            unsigned long long supLo = 0, supHi = 0, kpLo = 0, kpHi = 0;
            for (int r = 0; r < K; ++r) {
                const int i = ord[wv][r];
                const bool dead = (i < 64) ? ((supLo >> i) & 1ull)
                                           : ((supHi >> (i - 64)) & 1ull);
                if (!dead) {
                    if (i < 64) kpLo |= (1ull << i);
                    else        kpHi |= (1ull << (i - 64));
                    supLo |= (unsigned long long)adj[i][0]
                           | ((unsigned long long)adj[i][1] << 32);
                    supHi |= (unsigned long long)adj[i][2]
                           | ((unsigned long long)adj[i][3] << 32);
                }
            }
            km[c][0] = (unsigned)kpLo;
            km[c][1] = (unsigned)(kpLo >> 32);
            km[c][2] = (unsigned)kpHi;
            km[c][3] = (unsigned)(kpHi >> 32);
        }
    }
    __syncthreads();

    // ---- output: rows r = n*C + c, fields [cls, x1,y1,x2,y2, score] * keep ----
    float* ob = out + (size_t)b * kOutF;
    for (int r = tid; r < kRows; r += kT) {
        const int n = r / kC;
        const int c = r - n * kC;
        const bool kp = (km[c][n >> 5] >> (n & 31)) & 1u;
        const float m = kp ? 1.f : 0.f;
        float v0 = m * (float)c;
        float v1 = m * bxs[n * 4 + 0];
        float v2 = m * bxs[n * 4 + 1];
        float v3 = m * bxs[n * 4 + 2];
        float v4 = m * bxs[n * 4 + 3];
        float v5 = m * scT[c * kN + n];
        float2* o2 = reinterpret_cast<float2*>(ob + (size_t)r * 6);
        o2[0] = make_float2(v0, v1);
        o2[1] = make_float2(v2, v3);
        o2[2] = make_float2(v4, v5);
    }
}

extern "C" void kernel_launch(void* const* d_in, const int* in_sizes, int n_in,
                              void* d_out, int out_size, void* d_ws, size_t ws_size,
                              hipStream_t stream) {
    const float* x = (const float*)d_in[0];
    float* out = (float*)d_out;
    const int B = in_sizes[0] / (kS * kS * kFeat);   // 1024
    hipLaunchKernelGGL(yolo_head_kernel, dim3(B), dim3(kT), 0, stream, x, out);
}